// Round 6
// baseline (579.989 us; speedup 1.0000x reference)
//
#include <hip/hip_runtime.h>
#include <math.h>

// Problem constants: B=4, GL=4, GF=128, N=1024, CS=32, CN=16, NA=16, S=512
//
// Flat views (fp32, per b):
//  X  : [512 k][1024 n]
//  U  : [128 c][1024 n] ; P2 view: [1024 m][128 q], q=k*32+i, scale sc[l], l=m>>8
//  S  : [1024 m][512 ju]  (UNsquashed; MS holds squash scales)   ju=j*32+u
//  MS : [1024 m][32 u]    squash scale per (m,u)
//  UH : [8192]            u_hat for aspect routing, e = i*512 + j*32 + u

static constexpr int OFF_U  = 0;          // 524288
static constexpr int OFF_S  = 524288;     // 2097152 (also Upart[4][524288])
static constexpr int OFF_SS = 2621440;    // 16
static constexpr int OFF_BG = 2621456;    // 2048
static constexpr int OFF_G  = 2623504;    // 2048
static constexpr int OFF_VA = 2625552;    // 2048
static constexpr int OFF_MS = 2627600;    // 131072
static constexpr int OFF_UH = 2758672;    // 32768

#define NBLK 256

// ---------------------------------------------------------------------------
// Device-scope grid barrier for a plain (non-cooperative) persistent launch.
// Co-residency by capacity: 51456 B LDS/block -> >=2 blocks/CU, 4 waves/block
// -> total capacity >=512 blocks > NBLK=256, so all blocks are resident before
// any spin. All barrier state ops are device-scope atomics (cross-XCD
// coherent); __threadfence() emits the agent-scope L2 writeback/invalidate
// that makes ordinary-store data handoffs visible across XCDs.
// State persists across graph replays: g_cnt always returns to 0, g_gen is
// monotonic (equality test is wrap-safe).
__device__ unsigned g_cnt = 0;
__device__ unsigned g_gen = 0;

__device__ __forceinline__ void gbar()
{
    __syncthreads();
    if (threadIdx.x == 0) {
        __threadfence();                               // release: wb L2
        const unsigned gen = atomicAdd(&g_gen, 0u);    // read current generation
        if (atomicAdd(&g_cnt, 1u) == NBLK - 1u) {
            atomicExch(&g_cnt, 0u);                    // atomic reset (XCD-safe)
            __threadfence();
            atomicAdd(&g_gen, 1u);
        } else {
            while (atomicAdd(&g_gen, 0u) == gen) { __builtin_amdgcn_s_sleep(8); }
        }
        __threadfence();                               // acquire: inv L1/L2
    }
    __syncthreads();
}

// ---------------------------------------------------------------------------
__global__ void __launch_bounds__(256, 1) k_mega(
    const float* __restrict__ X,  const float* __restrict__ Wp,
    const float* __restrict__ bp, const float* __restrict__ Wg,
    const float* __restrict__ Wa, const float* __restrict__ Wsp,
    float* __restrict__ ws, float* __restrict__ out)
{
    __shared__ float smem[12864];   // 51456 B, max over phases (tbu)
    const int bid = blockIdx.x;
    const int t = threadIdx.x;

    float* U  = ws + OFF_U;
    float* S  = ws + OFF_S;     // doubles as Upart[4][b][...] before reduceU
    float* SS = ws + OFF_SS;
    float* Bg = ws + OFF_BG;
    float* G  = ws + OFF_G;
    float* VA = ws + OFF_VA;
    float* MS = ws + OFF_MS;
    float* UH = ws + OFF_UH;

    // ---- P0: zero SS(16)+Bg(2048)+G(2048) (contiguous), block 0 only ------
    if (bid == 0) {
        for (int i = t; i < 4112; i += 256) SS[i] = 0.f;
    }

    // ---- P1: primary partial GEMM, 512 units (ct2 x nt16 x b4 x ks4) ------
    {
        float* Wt = smem;   // 128*68
        for (int rep = 0; rep < 2; ++rep) {
            const int u = bid + rep * 256;
            const int ct = u & 1, nt = (u >> 1) & 15;
            const int z = u >> 5, b = z >> 2, ks = z & 3;
            const int tn = t & 15, tc = t >> 4;
            const int c0 = ct * 64, n0 = nt * 64;
            __syncthreads();
#pragma unroll
            for (int i = 0; i < 8; ++i) {
                const int idx = t + i * 256;
                const int c = idx >> 5, k4 = idx & 31;
                const float4 wv = *(const float4*)&Wp[(size_t)(c0 + c) * 512 + ks * 128 + k4 * 4];
                Wt[(k4 * 4 + 0) * 68 + c] = wv.x;
                Wt[(k4 * 4 + 1) * 68 + c] = wv.y;
                Wt[(k4 * 4 + 2) * 68 + c] = wv.z;
                Wt[(k4 * 4 + 3) * 68 + c] = wv.w;
            }
            __syncthreads();
            float acc[4][4] = {};
            const float* Xp = X + (size_t)b * 524288 + (size_t)(ks * 128) * 1024 + n0 + tn * 4;
#pragma unroll 4
            for (int k = 0; k < 128; ++k) {
                const float4 xv = *(const float4*)(Xp + (size_t)k * 1024);
                const float4 wv = *(const float4*)&Wt[k * 68 + tc * 4];
                const float w[4] = {wv.x, wv.y, wv.z, wv.w};
                const float x[4] = {xv.x, xv.y, xv.z, xv.w};
#pragma unroll
                for (int ci = 0; ci < 4; ++ci)
#pragma unroll
                    for (int ni = 0; ni < 4; ++ni)
                        acc[ci][ni] = fmaf(w[ci], x[ni], acc[ci][ni]);
            }
            float* up = S + (size_t)ks * 524288 + (size_t)b * 131072;
#pragma unroll
            for (int ci = 0; ci < 4; ++ci)
                *(float4*)&up[(size_t)(c0 + tc * 4 + ci) * 1024 + n0 + tn * 4] =
                    make_float4(acc[ci][0], acc[ci][1], acc[ci][2], acc[ci][3]);
        }
    }
    gbar();

    // ---- P2: U = sum_ks Upart + bp, SS = sum of squares. 128 units --------
    if (bid < 128) {
        float* red = smem;
        const int b = bid >> 5, cg = bid & 31;
        float ssq = 0.f;
#pragma unroll
        for (int i = 0; i < 4; ++i) {
            const int c = cg * 4 + i;
            const int f4 = b * 32768 + c * 256 + t;
            float4 s = ((const float4*)S)[f4];
#pragma unroll
            for (int ks = 1; ks < 4; ++ks) {
                const float4 p = ((const float4*)S)[ks * 131072 + f4];
                s.x += p.x; s.y += p.y; s.z += p.z; s.w += p.w;
            }
            const float bv = bp[c];
            s.x += bv; s.y += bv; s.z += bv; s.w += bv;
            ssq = fmaf(s.x, s.x, ssq); ssq = fmaf(s.y, s.y, ssq);
            ssq = fmaf(s.z, s.z, ssq); ssq = fmaf(s.w, s.w, ssq);
            ((float4*)U)[f4] = s;
        }
        red[t] = ssq;
        __syncthreads();
        for (int s = 128; s > 0; s >>= 1) {
            if (t < s) red[t] += red[t + s];
            __syncthreads();
        }
        if (t == 0) atomicAdd(&SS[b * 4 + (cg >> 3)], red[0]);
    }
    gbar();

    // ---- routing iterations ----------------------------------------------
    for (int it = 0; it < 3; ++it) {
        // P3: smatmul, 512 units (mt16 x jt8 x b4)
        {
            float* Pt  = smem;          // 64*65
            float* Ct  = smem + 4160;   // 64*65
            float* cls = smem + 8320;   // 512
            for (int rep = 0; rep < 2; ++rep) {
                const int u = bid + rep * 256;
                const int mt = u & 15, jt = (u >> 4) & 7, b = u >> 7;
                const int tj = t & 15, tm = t >> 4;
                __syncthreads();
                if (t < 32) {
                    float vals[16];
                    float mx = -1e30f;
                    for (int j = 0; j < 16; ++j) { vals[j] = Bg[b * 512 + t * 16 + j]; mx = fmaxf(mx, vals[j]); }
                    float sum = 0.f;
                    for (int j = 0; j < 16; ++j) { vals[j] = expf(vals[j] - mx); sum += vals[j]; }
                    const float inv = 1.f / sum;
                    for (int j = 0; j < 16; ++j) cls[t * 16 + j] = vals[j] * inv;
                }
                const float ssv = SS[b * 4 + (mt >> 2)];
                const float sc = sqrtf(ssv) / (1.f + ssv);
                float acc[4][4] = {};
                const float* Ub = U + (size_t)b * 131072 + (size_t)mt * 64 * 128;
                __syncthreads();
                for (int kc = 0; kc < 2; ++kc) {
                    for (int x = t; x < 64 * 64; x += 256) {
                        const int r = x >> 6, cq = x & 63;
                        Pt[r * 65 + cq] = Ub[r * 128 + kc * 64 + cq] * sc;
                        const int q = kc * 64 + cq;
                        const int i = q & 31, kk = q >> 5;
                        const int ju = jt * 64 + r;
                        const int j = ju >> 5, uu = ju & 31;
                        Ct[r * 65 + cq] = cls[i * 16 + j] * Wg[((i * 16 + j) * 32 + uu) * 4 + kk];
                    }
                    __syncthreads();
                    for (int q = 0; q < 64; ++q) {
                        float pv[4], cv[4];
#pragma unroll
                        for (int mm = 0; mm < 4; ++mm) pv[mm] = Pt[(tm * 4 + mm) * 65 + q];
#pragma unroll
                        for (int jj = 0; jj < 4; ++jj) cv[jj] = Ct[(tj * 4 + jj) * 65 + q];
#pragma unroll
                        for (int mm = 0; mm < 4; ++mm)
#pragma unroll
                            for (int jj = 0; jj < 4; ++jj)
                                acc[mm][jj] = fmaf(pv[mm], cv[jj], acc[mm][jj]);
                    }
                    __syncthreads();
                }
#pragma unroll
                for (int mm = 0; mm < 4; ++mm) {
                    float4 w = make_float4(acc[mm][0], acc[mm][1], acc[mm][2], acc[mm][3]);
                    *(float4*)(S + (size_t)b * 524288 + (size_t)(mt * 64 + tm * 4 + mm) * 512
                                 + jt * 64 + tj * 4) = w;
                }
            }
        }
        gbar();

        if (it < 2) {
            // P4: mag -> MS, 512 units (mg128 x b4), 8 m rows each
            for (int rep = 0; rep < 2; ++rep) {
                const int u = bid + rep * 256;
                const int b = u >> 7, mg = u & 127;
                const int uu = t & 31, ml = t >> 5;
                const int m = mg * 8 + ml;
                const float* row = S + (size_t)b * 524288 + (size_t)m * 512;
                float mag = 0.f;
#pragma unroll
                for (int j = 0; j < 16; ++j) { const float v = row[j * 32 + uu]; mag = fmaf(v, v, mag); }
                MS[b * 32768 + m * 32 + uu] = sqrtf(mag) / (1.f + mag);
            }
            gbar();

            // P5: tbu -> Bg, 512 units (jt8 x mc16 x b4)
            {
                float* Ps  = smem;           // 64*132
                float* Vs  = smem + 8448;    // 64*68
                float* bup = smem + 12800;   // 64
                for (int rep = 0; rep < 2; ++rep) {
                    const int u = bid + rep * 256;
                    const int jt = u & 7, mc = (u >> 3) & 15, b = u >> 7;
                    const int tq = t & 31, tjv = t >> 5;
                    const int m0 = mc * 64;
                    __syncthreads();
                    if (t < 64) bup[t] = 0.f;
                    const float ssv = SS[b * 4 + (mc >> 2)];
                    const float sc = sqrtf(ssv) / (1.f + ssv);
#pragma unroll
                    for (int i = 0; i < 8; ++i) {
                        const int f4 = t + i * 256;
                        const int r = f4 >> 5, q4 = f4 & 31;
                        float4 v = *(const float4*)&U[(size_t)b * 131072 + (size_t)(m0 + r) * 128 + q4 * 4];
                        v.x *= sc; v.y *= sc; v.z *= sc; v.w *= sc;
                        *(float4*)&Ps[r * 132 + q4 * 4] = v;
                    }
#pragma unroll
                    for (int i = 0; i < 4; ++i) {
                        const int f4 = t + i * 256;
                        const int r = f4 >> 4, c4 = f4 & 15;
                        const int m = m0 + r;
                        float4 v = *(const float4*)&S[(size_t)b * 524288 + (size_t)m * 512 + jt * 64 + c4 * 4];
                        const int ub = (c4 * 4) & 31;
                        const float* msp = MS + b * 32768 + m * 32;
                        v.x *= msp[ub + 0]; v.y *= msp[ub + 1]; v.z *= msp[ub + 2]; v.w *= msp[ub + 3];
                        *(float4*)&Vs[r * 68 + c4 * 4] = v;
                    }
                    __syncthreads();
                    float acc[4][8] = {};
#pragma unroll 2
                    for (int m = 0; m < 64; ++m) {
                        const float4 p4 = *(const float4*)&Ps[m * 132 + tq * 4];
                        const float4 va = *(const float4*)&Vs[m * 68 + tjv * 8];
                        const float4 vb = *(const float4*)&Vs[m * 68 + tjv * 8 + 4];
                        const float pv[4] = {p4.x, p4.y, p4.z, p4.w};
                        const float vv[8] = {va.x, va.y, va.z, va.w, vb.x, vb.y, vb.z, vb.w};
#pragma unroll
                        for (int qi = 0; qi < 4; ++qi)
#pragma unroll
                            for (int ji = 0; ji < 8; ++ji)
                                acc[qi][ji] = fmaf(pv[qi], vv[ji], acc[qi][ji]);
                    }
                    const int k = tq >> 3;
                    const int j_loc = tjv >> 2;
                    const int j = jt * 2 + j_loc;
                    const int u0 = (tjv & 3) * 8;
#pragma unroll
                    for (int qi = 0; qi < 4; ++qi) {
                        const int i = (tq & 7) * 4 + qi;
                        const float* wp = Wg + ((i * 16 + j) * 32) * 4 + k;
                        float s = 0.f;
#pragma unroll
                        for (int ji = 0; ji < 8; ++ji)
                            s = fmaf(wp[(u0 + ji) * 4], acc[qi][ji], s);
                        s += __shfl_xor(s, 8);
                        s += __shfl_xor(s, 16);
                        s += __shfl_xor(s, 32);
                        if ((t & 56) == 0) atomicAdd(&bup[i * 2 + j_loc], s);
                    }
                    __syncthreads();
                    if (t < 64) {
                        const int ii = t >> 1, jl = t & 1;
                        atomicAdd(&Bg[b * 512 + ii * 16 + jt * 2 + jl], bup[t] * (1.f / 1024.f));
                    }
                }
            }
            gbar();
        } else {
            // P6: maggmean -> G, 128 units (mt32 x b4)
            if (bid < 128) {
                float* gacc = smem;   // 512
                const int mt = bid & 31, b = bid >> 5;
                gacc[t] = 0.f; gacc[t + 256] = 0.f;
                const int uu = t & 31, mlg = t >> 5;
                const int m0 = mt * 32 + mlg * 4;
                float preg[16];
#pragma unroll
                for (int j = 0; j < 16; ++j) preg[j] = 0.f;
                __syncthreads();
#pragma unroll
                for (int mi = 0; mi < 4; ++mi) {
                    const float* row = S + (size_t)b * 524288 + (size_t)(m0 + mi) * 512;
                    float sv[16];
                    float mag = 0.f;
#pragma unroll
                    for (int j = 0; j < 16; ++j) { sv[j] = row[j * 32 + uu]; mag = fmaf(sv[j], sv[j], mag); }
                    const float msc = sqrtf(mag) / (1.f + mag);
#pragma unroll
                    for (int j = 0; j < 16; ++j) preg[j] = fmaf(sv[j], msc, preg[j]);
                }
#pragma unroll
                for (int j = 0; j < 16; ++j) atomicAdd(&gacc[j * 32 + uu], preg[j]);
                __syncthreads();
                atomicAdd(&G[b * 512 + t], gacc[t] * (1.f / 1024.f));
                atomicAdd(&G[b * 512 + 256 + t], gacc[t + 256] * (1.f / 1024.f));
            }
            gbar();
        }
    }

    // ---- P7: uhat, 32 units (slice8 x b4) --------------------------------
    if (bid < 32) {
        float* g     = smem;          // 512
        float* cond  = smem + 512;    // 512
        float* score = smem + 1024;   // 16
        float* red   = smem + 1040;   // 16
        const int slice = bid & 7, b = bid >> 3;
        g[t] = G[b * 512 + t];
        g[t + 256] = G[b * 512 + 256 + t];
        __syncthreads();
        if (t < 16) {
            float s = 0.f;
            for (int uu = 0; uu < 32; ++uu) s = fmaf(g[t * 32 + uu], Wa[uu], s);
            red[t] = s;
        }
        __syncthreads();
        if (t == 0) {
            float mx = -1e30f;
            for (int j = 0; j < 16; ++j) mx = fmaxf(mx, red[j]);
            float sum = 0.f;
            for (int j = 0; j < 16; ++j) { score[j] = expf(red[j] - mx); sum += score[j]; }
            const float inv = 1.f / sum;
            for (int j = 0; j < 16; ++j) score[j] *= inv;
        }
        __syncthreads();
        cond[t] = g[t] * score[t >> 5];
        cond[t + 256] = g[t + 256] * score[(t + 256) >> 5];
        __syncthreads();
        const int e0 = slice * 1024 + t * 4;
        const int i = e0 >> 9;
        const float* cp = cond + i * 32;
        const float* wp = Wsp + (size_t)e0 * 32;
        float res[4];
#pragma unroll
        for (int jj = 0; jj < 4; ++jj) {
            float s = 0.f;
#pragma unroll
            for (int k8 = 0; k8 < 8; ++k8) {
                const float4 w = *(const float4*)(wp + jj * 32 + k8 * 4);
                s = fmaf(w.x, cp[k8 * 4 + 0], s);
                s = fmaf(w.y, cp[k8 * 4 + 1], s);
                s = fmaf(w.z, cp[k8 * 4 + 2], s);
                s = fmaf(w.w, cp[k8 * 4 + 3], s);
            }
            res[jj] = s;
        }
        ((float4*)UH)[(b * 8192 + e0) >> 2] = make_float4(res[0], res[1], res[2], res[3]);
    }
    gbar();

    // ---- P8: aspect routing, 4 units -------------------------------------
    if (bid < 4) {
        float* uh   = smem;           // 8192
        float* ba   = smem + 8192;    // 256
        float* cc   = smem + 8448;    // 256
        float* sbuf = smem + 8704;    // 512
        float* msc  = smem + 9216;    // 32
        const int b = bid;
#pragma unroll
        for (int i = 0; i < 8; ++i)
            ((float4*)uh)[i * 256 + t] = ((const float4*)UH)[b * 2048 + i * 256 + t];
        ba[t] = 0.f;
        __syncthreads();
        for (int it = 0; it < 3; ++it) {
            if (t < 16) {
                float mx = -1e30f;
                for (int j = 0; j < 16; ++j) mx = fmaxf(mx, ba[t * 16 + j]);
                float sum = 0.f;
                for (int j = 0; j < 16; ++j) { cc[t * 16 + j] = expf(ba[t * 16 + j] - mx); sum += cc[t * 16 + j]; }
                const float inv = 1.f / sum;
                for (int j = 0; j < 16; ++j) cc[t * 16 + j] *= inv;
            }
            __syncthreads();
            for (int h = 0; h < 2; ++h) {
                const int e = h * 256 + t;
                const int j = e >> 5;
                float s = 0.f;
                for (int i = 0; i < 16; ++i) s = fmaf(cc[i * 16 + j], uh[i * 512 + e], s);
                sbuf[e] = s;
            }
            __syncthreads();
            if (t < 32) {
                float mg = 0.f;
                for (int j = 0; j < 16; ++j) { const float x = sbuf[j * 32 + t]; mg = fmaf(x, x, mg); }
                msc[t] = sqrtf(mg) / (1.f + mg);
            }
            __syncthreads();
            for (int h = 0; h < 2; ++h) {
                const int e = h * 256 + t;
                sbuf[e] *= msc[e & 31];
            }
            __syncthreads();
            if (it < 2) {
                const int i = t >> 4, j = t & 15;
                float s = 0.f;
                for (int uu = 0; uu < 32; ++uu) s = fmaf(uh[i * 512 + j * 32 + uu], sbuf[j * 32 + uu], s);
                ba[t] += s;
                __syncthreads();
            }
        }
        VA[b * 512 + t] = sbuf[t];
        VA[b * 512 + 256 + t] = sbuf[256 + t];
    }
    gbar();

    // ---- P9: broadcast VA to all 512 rows per example --------------------
#pragma unroll
    for (int i = 0; i < 4; ++i) {
        const int idx = bid * 1024 + i * 256 + t;   // float4 index, 262144 total
        const int b = idx >> 16;
        const int jv4 = idx & 127;
        ((float4*)out)[idx] = ((const float4*)VA)[b * 128 + jv4];
    }
}

// ---------------------------------------------------------------------------
extern "C" void kernel_launch(void* const* d_in, const int* in_sizes, int n_in,
                              void* d_out, int out_size, void* d_ws, size_t ws_size,
                              hipStream_t stream)
{
    const float* X   = (const float*)d_in[0];
    // d_in[1] = hidden — provably unused (softmax shift-invariance kills it)
    const float* Wp  = (const float*)d_in[2];
    const float* bp  = (const float*)d_in[3];
    const float* Wg  = (const float*)d_in[4];
    const float* Wa  = (const float*)d_in[5];
    const float* Wsp = (const float*)d_in[6];
    float* out = (float*)d_out;
    float* ws  = (float*)d_ws;

    k_mega<<<dim3(NBLK), dim3(256), 0, stream>>>(X, Wp, bp, Wg, Wa, Wsp, ws, out);
}

// Round 8
// 474.276 us; speedup vs baseline: 1.2229x; 1.2229x over previous
//
#include <hip/hip_runtime.h>
#include <math.h>

// Problem constants: B=4, GL=4, GF=128, N=1024, CS=32, CN=16, NA=16, S=512
//
// Flat views (fp32, per b):
//  X  : [512 k][1024 n]
//  U  : [128 c][1024 n] ; P2 view: [1024 m][128 q], q=k*32+i, scale sc[l], l=m>>8
//  S  : [1024 m][512 ju]  (UNsquashed; squash scales recomputed where needed)
//  UH : [8192]            u_hat for aspect routing, e = i*512 + j*32 + u

static constexpr int OFF_U  = 0;          // 524288
static constexpr int OFF_S  = 524288;     // 2097152 (also Upart[4][524288])
static constexpr int OFF_SS = 2621440;    // 16
static constexpr int OFF_BG = 2621456;    // 2048
static constexpr int OFF_G  = 2623504;    // 2048
static constexpr int OFF_UH = 2625552;    // 32768

#define NBLK 256

// ---------------------------------------------------------------------------
// Device-scope grid barrier, contention-hardened:
//  - cnt (g_state[0]) and gen (g_state[64]) live 256 B apart -> arrival RMWs
//    never contend with spin traffic on the same line.
//  - spinners use device-scope atomic LOADS (served concurrently), not RMWs.
//  - release/acquire via __threadfence (L2 wb/inv for ordinary-store handoff).
// Co-residency by capacity: 59.6 KB LDS/block, 4 waves/block -> 1 block/CU,
// 256 blocks on 256 CUs all resident before any spin.
// State persists across graph replays: cnt returns to 0 after every barrier,
// gen is monotonic (equality spin is wrap-safe).
__device__ unsigned g_state[128] = {};

__device__ __forceinline__ void gbar()
{
    __syncthreads();
    if (threadIdx.x == 0) {
        __threadfence();   // release: make this block's stores visible
        const unsigned gen =
            __hip_atomic_load(&g_state[64], __ATOMIC_RELAXED, __HIP_MEMORY_SCOPE_AGENT);
        const unsigned arrived =
            __hip_atomic_fetch_add(&g_state[0], 1u, __ATOMIC_RELAXED, __HIP_MEMORY_SCOPE_AGENT);
        if (arrived == NBLK - 1u) {
            __hip_atomic_store(&g_state[0], 0u, __ATOMIC_RELAXED, __HIP_MEMORY_SCOPE_AGENT);
            __hip_atomic_fetch_add(&g_state[64], 1u, __ATOMIC_RELEASE, __HIP_MEMORY_SCOPE_AGENT);
        } else {
            while (__hip_atomic_load(&g_state[64], __ATOMIC_RELAXED,
                                     __HIP_MEMORY_SCOPE_AGENT) == gen)
                __builtin_amdgcn_s_sleep(8);
        }
        __threadfence();   // acquire: invalidate stale caches
    }
    __syncthreads();
}

// ---------------------------------------------------------------------------
__global__ void __launch_bounds__(256, 1) k_mega(
    const float* __restrict__ X,  const float* __restrict__ Wp,
    const float* __restrict__ bp, const float* __restrict__ Wg,
    const float* __restrict__ Wa, const float* __restrict__ Wsp,
    float* __restrict__ ws, float* __restrict__ out)
{
    __shared__ float smem[14912];   // 59648 B, max over phases (P5 tbu)
    const int bid = blockIdx.x;
    const int t = threadIdx.x;

    float* U  = ws + OFF_U;
    float* S  = ws + OFF_S;     // doubles as Upart[4][b][...] before P2
    float* SS = ws + OFF_SS;
    float* Bg = ws + OFF_BG;
    float* G  = ws + OFF_G;
    float* UH = ws + OFF_UH;

    // ---- P0: zero SS(16)+Bg(2048)+G(2048) (contiguous), block 0 only ------
    if (bid == 0) {
        for (int i = t; i < 4112; i += 256) SS[i] = 0.f;
    }

    // ---- P1: primary partial GEMM, 512 units (ct2 x nt16 x b4 x ks4) ------
    {
        float* Wt = smem;   // 128*68
        for (int rep = 0; rep < 2; ++rep) {
            const int u = bid + rep * 256;
            const int ct = u & 1, nt = (u >> 1) & 15;
            const int z = u >> 5, b = z >> 2, ks = z & 3;
            const int tn = t & 15, tc = t >> 4;
            const int c0 = ct * 64, n0 = nt * 64;
            __syncthreads();
#pragma unroll
            for (int i = 0; i < 8; ++i) {
                const int idx = t + i * 256;
                const int c = idx >> 5, k4 = idx & 31;
                const float4 wv = *(const float4*)&Wp[(size_t)(c0 + c) * 512 + ks * 128 + k4 * 4];
                Wt[(k4 * 4 + 0) * 68 + c] = wv.x;
                Wt[(k4 * 4 + 1) * 68 + c] = wv.y;
                Wt[(k4 * 4 + 2) * 68 + c] = wv.z;
                Wt[(k4 * 4 + 3) * 68 + c] = wv.w;
            }
            __syncthreads();
            float acc[4][4] = {};
            const float* Xp = X + (size_t)b * 524288 + (size_t)(ks * 128) * 1024 + n0 + tn * 4;
#pragma unroll 4
            for (int k = 0; k < 128; ++k) {
                const float4 xv = *(const float4*)(Xp + (size_t)k * 1024);
                const float4 wv = *(const float4*)&Wt[k * 68 + tc * 4];
                const float w[4] = {wv.x, wv.y, wv.z, wv.w};
                const float x[4] = {xv.x, xv.y, xv.z, xv.w};
#pragma unroll
                for (int ci = 0; ci < 4; ++ci)
#pragma unroll
                    for (int ni = 0; ni < 4; ++ni)
                        acc[ci][ni] = fmaf(w[ci], x[ni], acc[ci][ni]);
            }
            float* up = S + (size_t)ks * 524288 + (size_t)b * 131072;
#pragma unroll
            for (int ci = 0; ci < 4; ++ci)
                *(float4*)&up[(size_t)(c0 + tc * 4 + ci) * 1024 + n0 + tn * 4] =
                    make_float4(acc[ci][0], acc[ci][1], acc[ci][2], acc[ci][3]);
        }
    }
    gbar();   // B1

    // ---- P2: U = sum_ks Upart + bp, SS = sum of squares. 128 units --------
    if (bid < 128) {
        float* red = smem;
        const int b = bid >> 5, cg = bid & 31;
        float ssq = 0.f;
#pragma unroll
        for (int i = 0; i < 4; ++i) {
            const int c = cg * 4 + i;
            const int f4 = b * 32768 + c * 256 + t;
            float4 s = ((const float4*)S)[f4];
#pragma unroll
            for (int ks = 1; ks < 4; ++ks) {
                const float4 p = ((const float4*)S)[ks * 131072 + f4];
                s.x += p.x; s.y += p.y; s.z += p.z; s.w += p.w;
            }
            const float bv = bp[c];
            s.x += bv; s.y += bv; s.z += bv; s.w += bv;
            ssq = fmaf(s.x, s.x, ssq); ssq = fmaf(s.y, s.y, ssq);
            ssq = fmaf(s.z, s.z, ssq); ssq = fmaf(s.w, s.w, ssq);
            ((float4*)U)[f4] = s;
        }
        red[t] = ssq;
        __syncthreads();
        for (int s = 128; s > 0; s >>= 1) {
            if (t < s) red[t] += red[t + s];
            __syncthreads();
        }
        if (t == 0) atomicAdd(&SS[b * 4 + (cg >> 3)], red[0]);
    }
    gbar();   // B2

    // ---- routing iterations ----------------------------------------------
    for (int it = 0; it < 3; ++it) {
        // P3: smatmul, 512 units (mt16 x jt8 x b4)
        {
            float* Pt  = smem;          // 64*65
            float* Ct  = smem + 4160;   // 64*65
            float* cls = smem + 8320;   // 512
            for (int rep = 0; rep < 2; ++rep) {
                const int u = bid + rep * 256;
                const int mt = u & 15, jt = (u >> 4) & 7, b = u >> 7;
                const int tj = t & 15, tm = t >> 4;
                __syncthreads();
                if (t < 32) {
                    float vals[16];
                    float mx = -1e30f;
                    for (int j = 0; j < 16; ++j) { vals[j] = Bg[b * 512 + t * 16 + j]; mx = fmaxf(mx, vals[j]); }
                    float sum = 0.f;
                    for (int j = 0; j < 16; ++j) { vals[j] = expf(vals[j] - mx); sum += vals[j]; }
                    const float inv = 1.f / sum;
                    for (int j = 0; j < 16; ++j) cls[t * 16 + j] = vals[j] * inv;
                }
                const float ssv = SS[b * 4 + (mt >> 2)];
                const float sc = sqrtf(ssv) / (1.f + ssv);
                float acc[4][4] = {};
                const float* Ub = U + (size_t)b * 131072 + (size_t)mt * 64 * 128;
                __syncthreads();
                for (int kc = 0; kc < 2; ++kc) {
                    for (int x = t; x < 64 * 64; x += 256) {
                        const int r = x >> 6, cq = x & 63;
                        Pt[r * 65 + cq] = Ub[r * 128 + kc * 64 + cq] * sc;
                        const int q = kc * 64 + cq;
                        const int i = q & 31, kk = q >> 5;
                        const int ju = jt * 64 + r;
                        const int j = ju >> 5, uu = ju & 31;
                        Ct[r * 65 + cq] = cls[i * 16 + j] * Wg[((i * 16 + j) * 32 + uu) * 4 + kk];
                    }
                    __syncthreads();
                    for (int q = 0; q < 64; ++q) {
                        float pv[4], cv[4];
#pragma unroll
                        for (int mm = 0; mm < 4; ++mm) pv[mm] = Pt[(tm * 4 + mm) * 65 + q];
#pragma unroll
                        for (int jj = 0; jj < 4; ++jj) cv[jj] = Ct[(tj * 4 + jj) * 65 + q];
#pragma unroll
                        for (int mm = 0; mm < 4; ++mm)
#pragma unroll
                            for (int jj = 0; jj < 4; ++jj)
                                acc[mm][jj] = fmaf(pv[mm], cv[jj], acc[mm][jj]);
                    }
                    __syncthreads();
                }
#pragma unroll
                for (int mm = 0; mm < 4; ++mm) {
                    float4 w = make_float4(acc[mm][0], acc[mm][1], acc[mm][2], acc[mm][3]);
                    *(float4*)(S + (size_t)b * 524288 + (size_t)(mt * 64 + tm * 4 + mm) * 512
                                 + jt * 64 + tj * 4) = w;
                }
            }
        }
        gbar();   // B3/B5/B7

        if (it < 2) {
            // P5: tbu -> Bg, 512 units (jt8 x mc16 x b4); squash scale for the
            // 64-m chunk recomputed in-block from S (no MS pass, no extra barrier)
            {
                float* Ps  = smem;            // 64*132 = 8448
                float* Vs  = smem + 8448;     // 64*68  = 4352
                float* msS = smem + 12800;    // 64*32  = 2048
                float* bup = smem + 14848;    // 64
                for (int rep = 0; rep < 2; ++rep) {
                    const int u = bid + rep * 256;
                    const int jt = u & 7, mc = (u >> 3) & 15, b = u >> 7;
                    const int tq = t & 31, tjv = t >> 5;
                    const int m0 = mc * 64;
                    __syncthreads();
                    if (t < 64) bup[t] = 0.f;
                    // mag slice: thread (uu=t&31, rg=t>>5) does rows rg*8+mi
                    {
                        const int uu = t & 31, rg = t >> 5;
#pragma unroll
                        for (int mi = 0; mi < 8; ++mi) {
                            const int r = rg * 8 + mi;
                            const float* row = S + (size_t)b * 524288 + (size_t)(m0 + r) * 512;
                            float mag = 0.f;
#pragma unroll
                            for (int j = 0; j < 16; ++j) { const float v = row[j * 32 + uu]; mag = fmaf(v, v, mag); }
                            msS[r * 32 + uu] = sqrtf(mag) / (1.f + mag);
                        }
                    }
                    const float ssv = SS[b * 4 + (mc >> 2)];
                    const float sc = sqrtf(ssv) / (1.f + ssv);
                    __syncthreads();   // msS ready
#pragma unroll
                    for (int i = 0; i < 8; ++i) {
                        const int f4 = t + i * 256;
                        const int r = f4 >> 5, q4 = f4 & 31;
                        float4 v = *(const float4*)&U[(size_t)b * 131072 + (size_t)(m0 + r) * 128 + q4 * 4];
                        v.x *= sc; v.y *= sc; v.z *= sc; v.w *= sc;
                        *(float4*)&Ps[r * 132 + q4 * 4] = v;
                    }
#pragma unroll
                    for (int i = 0; i < 4; ++i) {
                        const int f4 = t + i * 256;
                        const int r = f4 >> 4, c4 = f4 & 15;
                        const int m = m0 + r;
                        float4 v = *(const float4*)&S[(size_t)b * 524288 + (size_t)m * 512 + jt * 64 + c4 * 4];
                        const int ub = (c4 * 4) & 31;
                        v.x *= msS[r * 32 + ub + 0]; v.y *= msS[r * 32 + ub + 1];
                        v.z *= msS[r * 32 + ub + 2]; v.w *= msS[r * 32 + ub + 3];
                        *(float4*)&Vs[r * 68 + c4 * 4] = v;
                    }
                    __syncthreads();
                    float acc[4][8] = {};
#pragma unroll 2
                    for (int m = 0; m < 64; ++m) {
                        const float4 p4 = *(const float4*)&Ps[m * 132 + tq * 4];
                        const float4 va = *(const float4*)&Vs[m * 68 + tjv * 8];
                        const float4 vb = *(const float4*)&Vs[m * 68 + tjv * 8 + 4];
                        const float pv[4] = {p4.x, p4.y, p4.z, p4.w};
                        const float vv[8] = {va.x, va.y, va.z, va.w, vb.x, vb.y, vb.z, vb.w};
#pragma unroll
                        for (int qi = 0; qi < 4; ++qi)
#pragma unroll
                            for (int ji = 0; ji < 8; ++ji)
                                acc[qi][ji] = fmaf(pv[qi], vv[ji], acc[qi][ji]);
                    }
                    const int k = tq >> 3;
                    const int j_loc = tjv >> 2;
                    const int j = jt * 2 + j_loc;
                    const int u0 = (tjv & 3) * 8;
#pragma unroll
                    for (int qi = 0; qi < 4; ++qi) {
                        const int i = (tq & 7) * 4 + qi;
                        const float* wp = Wg + ((i * 16 + j) * 32) * 4 + k;
                        float s = 0.f;
#pragma unroll
                        for (int ji = 0; ji < 8; ++ji)
                            s = fmaf(wp[(u0 + ji) * 4], acc[qi][ji], s);
                        s += __shfl_xor(s, 8);
                        s += __shfl_xor(s, 16);
                        s += __shfl_xor(s, 32);
                        if ((t & 56) == 0) atomicAdd(&bup[i * 2 + j_loc], s);
                    }
                    __syncthreads();
                    if (t < 64) {
                        const int ii = t >> 1, jl = t & 1;
                        atomicAdd(&Bg[b * 512 + ii * 16 + jt * 2 + jl], bup[t] * (1.f / 1024.f));
                    }
                }
            }
            gbar();   // B4/B6
        } else {
            // P6: maggmean -> G, 128 units (mt32 x b4)
            if (bid < 128) {
                float* gacc = smem;   // 512
                const int mt = bid & 31, b = bid >> 5;
                gacc[t] = 0.f; gacc[t + 256] = 0.f;
                const int uu = t & 31, mlg = t >> 5;
                const int m0 = mt * 32 + mlg * 4;
                float preg[16];
#pragma unroll
                for (int j = 0; j < 16; ++j) preg[j] = 0.f;
                __syncthreads();
#pragma unroll
                for (int mi = 0; mi < 4; ++mi) {
                    const float* row = S + (size_t)b * 524288 + (size_t)(m0 + mi) * 512;
                    float sv[16];
                    float mag = 0.f;
#pragma unroll
                    for (int j = 0; j < 16; ++j) { sv[j] = row[j * 32 + uu]; mag = fmaf(sv[j], sv[j], mag); }
                    const float msc = sqrtf(mag) / (1.f + mag);
#pragma unroll
                    for (int j = 0; j < 16; ++j) preg[j] = fmaf(sv[j], msc, preg[j]);
                }
#pragma unroll
                for (int j = 0; j < 16; ++j) atomicAdd(&gacc[j * 32 + uu], preg[j]);
                __syncthreads();
                atomicAdd(&G[b * 512 + t], gacc[t] * (1.f / 1024.f));
                atomicAdd(&G[b * 512 + 256 + t], gacc[t + 256] * (1.f / 1024.f));
            }
            gbar();   // B8
        }
    }

    // ---- P7: uhat, 32 units (slice8 x b4) --------------------------------
    if (bid < 32) {
        float* g     = smem;          // 512
        float* cond  = smem + 512;    // 512
        float* score = smem + 1024;   // 16
        float* red   = smem + 1040;   // 16
        const int slice = bid & 7, b = bid >> 3;
        g[t] = G[b * 512 + t];
        g[t + 256] = G[b * 512 + 256 + t];
        __syncthreads();
        if (t < 16) {
            float s = 0.f;
            for (int uu = 0; uu < 32; ++uu) s = fmaf(g[t * 32 + uu], Wa[uu], s);
            red[t] = s;
        }
        __syncthreads();
        if (t == 0) {
            float mx = -1e30f;
            for (int j = 0; j < 16; ++j) mx = fmaxf(mx, red[j]);
            float sum = 0.f;
            for (int j = 0; j < 16; ++j) { score[j] = expf(red[j] - mx); sum += score[j]; }
            const float inv = 1.f / sum;
            for (int j = 0; j < 16; ++j) score[j] *= inv;
        }
        __syncthreads();
        cond[t] = g[t] * score[t >> 5];
        cond[t + 256] = g[t + 256] * score[(t + 256) >> 5];
        __syncthreads();
        const int e0 = slice * 1024 + t * 4;
        const int i = e0 >> 9;
        const float* cp = cond + i * 32;
        const float* wp = Wsp + (size_t)e0 * 32;
        float res[4];
#pragma unroll
        for (int jj = 0; jj < 4; ++jj) {
            float s = 0.f;
#pragma unroll
            for (int k8 = 0; k8 < 8; ++k8) {
                const float4 w = *(const float4*)(wp + jj * 32 + k8 * 4);
                s = fmaf(w.x, cp[k8 * 4 + 0], s);
                s = fmaf(w.y, cp[k8 * 4 + 1], s);
                s = fmaf(w.z, cp[k8 * 4 + 2], s);
                s = fmaf(w.w, cp[k8 * 4 + 3], s);
            }
            res[jj] = s;
        }
        ((float4*)UH)[(b * 8192 + e0) >> 2] = make_float4(res[0], res[1], res[2], res[3]);
    }
    gbar();   // B9

    // ---- P8': aspect routing (redundant per 64-block group) + direct out --
    {
        float* uh   = smem;           // 8192
        float* ba   = smem + 8192;    // 256
        float* cc   = smem + 8448;    // 256
        float* sbuf = smem + 8704;    // 512
        float* msc  = smem + 9216;    // 32
        const int b = bid >> 6;
#pragma unroll
        for (int i = 0; i < 8; ++i)
            ((float4*)uh)[i * 256 + t] = ((const float4*)UH)[b * 2048 + i * 256 + t];
        ba[t] = 0.f;
        __syncthreads();
        for (int it = 0; it < 3; ++it) {
            if (t < 16) {
                float mx = -1e30f;
                for (int j = 0; j < 16; ++j) mx = fmaxf(mx, ba[t * 16 + j]);
                float sum = 0.f;
                for (int j = 0; j < 16; ++j) { cc[t * 16 + j] = expf(ba[t * 16 + j] - mx); sum += cc[t * 16 + j]; }
                const float inv = 1.f / sum;
                for (int j = 0; j < 16; ++j) cc[t * 16 + j] *= inv;
            }
            __syncthreads();
            for (int h = 0; h < 2; ++h) {
                const int e = h * 256 + t;
                const int j = e >> 5;
                float s = 0.f;
                for (int i = 0; i < 16; ++i) s = fmaf(cc[i * 16 + j], uh[i * 512 + e], s);
                sbuf[e] = s;
            }
            __syncthreads();
            if (t < 32) {
                float mg = 0.f;
                for (int j = 0; j < 16; ++j) { const float x = sbuf[j * 32 + t]; mg = fmaf(x, x, mg); }
                msc[t] = sqrtf(mg) / (1.f + mg);
            }
            __syncthreads();
            for (int h = 0; h < 2; ++h) {
                const int e = h * 256 + t;
                sbuf[e] *= msc[e & 31];
            }
            __syncthreads();
            if (it < 2) {
                const int i = t >> 4, j = t & 15;
                float s = 0.f;
                for (int uu = 0; uu < 32; ++uu) s = fmaf(uh[i * 512 + j * 32 + uu], sbuf[j * 32 + uu], s);
                ba[t] += s;
                __syncthreads();
            }
        }
        // write this block's slice of out directly from LDS (rows identical)
#pragma unroll
        for (int i = 0; i < 4; ++i) {
            const int idx = bid * 1024 + i * 256 + t;   // float4 index, 262144 total
            const int jv4 = idx & 127;                  // b = idx>>16 == bid>>6 by construction
            ((float4*)out)[idx] = *(const float4*)&sbuf[jv4 * 4];
        }
    }
}

// ---------------------------------------------------------------------------
extern "C" void kernel_launch(void* const* d_in, const int* in_sizes, int n_in,
                              void* d_out, int out_size, void* d_ws, size_t ws_size,
                              hipStream_t stream)
{
    const float* X   = (const float*)d_in[0];
    // d_in[1] = hidden — provably unused (softmax shift-invariance kills it)
    const float* Wp  = (const float*)d_in[2];
    const float* bp  = (const float*)d_in[3];
    const float* Wg  = (const float*)d_in[4];
    const float* Wa  = (const float*)d_in[5];
    const float* Wsp = (const float*)d_in[6];
    float* out = (float*)d_out;
    float* ws  = (float*)d_ws;

    k_mega<<<dim3(NBLK), dim3(256), 0, stream>>>(X, Wp, bp, Wg, Wa, Wsp, ws, out);
}

// Round 9
// 231.620 us; speedup vs baseline: 2.5040x; 2.0476x over previous
//
#include <hip/hip_runtime.h>
#include <math.h>

// Problem constants: B=4, GL=4, GF=128, N=1024, CS=32, CN=16, NA=16, S=512
//
// Flat views (fp32, per b):
//  X  : [512 k][1024 n]
//  U  : [128 c][1024 n] ; P2 view: [1024 m][128 q], q=k*32+i, scale sc[l], l=m>>8
//  S  : [1024 m][512 ju]  (UNsquashed; squash scales recomputed where needed)
//  UH : [8192]            u_hat for aspect routing, e = i*512 + j*32 + u

static constexpr int OFF_U  = 0;          // 524288
static constexpr int OFF_S  = 524288;     // 2097152 (also Upart[4][524288])
static constexpr int OFF_SS = 2621440;    // 16
static constexpr int OFF_BG = 2621456;    // 2048
static constexpr int OFF_G  = 2623504;    // 2048
static constexpr int OFF_UH = 2625552;    // 32768

// ---------------------------------------------------------------------------
// K1: partial U over K-window of 128: Upart[ks] = Wp[:,ks*128:+128] @ X[ks*128:+128,:]
// grid (2 ct, 16 nt, 16 z: b=z>>2, ks=z&3). Block (0,0,0) also zeroes SS/Bg/G
// (consumed only after the next kernel boundary).
__global__ void k_primary_part(const float* __restrict__ X, const float* __restrict__ Wp,
                               float* __restrict__ ws)
{
    __shared__ float Wt[128 * 68];
    float* Upart = ws + OFF_S;
    if (blockIdx.x == 0 && blockIdx.y == 0 && blockIdx.z == 0) {
        float* Z = ws + OFF_SS;
        for (int i = threadIdx.x; i < 4112; i += 256) Z[i] = 0.f;
    }
    const int ct = blockIdx.x, nt = blockIdx.y;
    const int b = blockIdx.z >> 2, ks = blockIdx.z & 3;
    const int t = threadIdx.x;
    const int tn = t & 15, tc = t >> 4;
    const int c0 = ct * 64, n0 = nt * 64;
#pragma unroll
    for (int i = 0; i < 8; ++i) {
        const int idx = t + i * 256;
        const int c = idx >> 5, k4 = idx & 31;
        const float4 wv = *(const float4*)&Wp[(size_t)(c0 + c) * 512 + ks * 128 + k4 * 4];
        Wt[(k4 * 4 + 0) * 68 + c] = wv.x;
        Wt[(k4 * 4 + 1) * 68 + c] = wv.y;
        Wt[(k4 * 4 + 2) * 68 + c] = wv.z;
        Wt[(k4 * 4 + 3) * 68 + c] = wv.w;
    }
    __syncthreads();
    float acc[4][4] = {};
    const float* Xp = X + (size_t)b * 524288 + (size_t)(ks * 128) * 1024 + n0 + tn * 4;
#pragma unroll 4
    for (int k = 0; k < 128; ++k) {
        const float4 xv = *(const float4*)(Xp + (size_t)k * 1024);
        const float4 wv = *(const float4*)&Wt[k * 68 + tc * 4];
        const float w[4] = {wv.x, wv.y, wv.z, wv.w};
        const float x[4] = {xv.x, xv.y, xv.z, xv.w};
#pragma unroll
        for (int ci = 0; ci < 4; ++ci)
#pragma unroll
            for (int ni = 0; ni < 4; ++ni)
                acc[ci][ni] = fmaf(w[ci], x[ni], acc[ci][ni]);
    }
    float* up = Upart + (size_t)ks * 524288 + (size_t)b * 131072;
#pragma unroll
    for (int ci = 0; ci < 4; ++ci)
        *(float4*)&up[(size_t)(c0 + tc * 4 + ci) * 1024 + n0 + tn * 4] =
            make_float4(acc[ci][0], acc[ci][1], acc[ci][2], acc[ci][3]);
}

// ---------------------------------------------------------------------------
// K2: U = sum_ks Upart + bp, SS[b][l] = sum of squares. grid 128.
__global__ void k_reduceU(const float* __restrict__ bp, float* __restrict__ ws)
{
    __shared__ float red[256];
    const float* Upart = ws + OFF_S;
    float* U  = ws + OFF_U;
    float* SS = ws + OFF_SS;
    const int blk = blockIdx.x, t = threadIdx.x;
    const int b = blk >> 5, cg = blk & 31;
    float ssq = 0.f;
#pragma unroll
    for (int i = 0; i < 4; ++i) {
        const int c = cg * 4 + i;
        const int f4 = b * 32768 + c * 256 + t;
        float4 s = ((const float4*)Upart)[f4];
#pragma unroll
        for (int ks = 1; ks < 4; ++ks) {
            const float4 p = ((const float4*)Upart)[ks * 131072 + f4];
            s.x += p.x; s.y += p.y; s.z += p.z; s.w += p.w;
        }
        const float bv = bp[c];
        s.x += bv; s.y += bv; s.z += bv; s.w += bv;
        ssq = fmaf(s.x, s.x, ssq); ssq = fmaf(s.y, s.y, ssq);
        ssq = fmaf(s.z, s.z, ssq); ssq = fmaf(s.w, s.w, ssq);
        ((float4*)U)[f4] = s;
    }
    red[t] = ssq;
    __syncthreads();
    for (int s = 128; s > 0; s >>= 1) {
        if (t < s) red[t] += red[t + s];
        __syncthreads();
    }
    if (t == 0) atomicAdd(&SS[b * 4 + (cg >> 3)], red[0]);
}

// ---------------------------------------------------------------------------
// K3: S[b][m][ju] = sum_q (U[m][q]*sc) * (cls[i][j]*Wg[i][j][u][k])
// grid (16 mt, 8 jt, 4 b), 64x64 tiles, K=128 in 2 chunks.
__global__ void k_smatmul(const float* __restrict__ Wg, float* __restrict__ ws)
{
    __shared__ float Pt[64 * 65];
    __shared__ float Ct[64 * 65];
    __shared__ float cls[512];
    const float* U  = ws + OFF_U;
    const float* SS = ws + OFF_SS;
    const float* Bg = ws + OFF_BG;
    float* S = ws + OFF_S;
    const int mt = blockIdx.x, jt = blockIdx.y, b = blockIdx.z;
    const int t = threadIdx.x;
    const int tj = t & 15, tm = t >> 4;
    if (t < 32) {
        float vals[16];
        float mx = -1e30f;
        for (int j = 0; j < 16; ++j) { vals[j] = Bg[b * 512 + t * 16 + j]; mx = fmaxf(mx, vals[j]); }
        float sum = 0.f;
        for (int j = 0; j < 16; ++j) { vals[j] = expf(vals[j] - mx); sum += vals[j]; }
        const float inv = 1.f / sum;
        for (int j = 0; j < 16; ++j) cls[t * 16 + j] = vals[j] * inv;
    }
    const float ssv = SS[b * 4 + (mt >> 2)];
    const float sc = sqrtf(ssv) / (1.f + ssv);
    float acc[4][4] = {};
    const float* Ub = U + (size_t)b * 131072 + (size_t)mt * 64 * 128;
    __syncthreads();
    for (int kc = 0; kc < 2; ++kc) {
        for (int x = t; x < 64 * 64; x += 256) {
            const int r = x >> 6, cq = x & 63;
            Pt[r * 65 + cq] = Ub[r * 128 + kc * 64 + cq] * sc;
            const int q = kc * 64 + cq;
            const int i = q & 31, kk = q >> 5;
            const int ju = jt * 64 + r;
            const int j = ju >> 5, uu = ju & 31;
            Ct[r * 65 + cq] = cls[i * 16 + j] * Wg[((i * 16 + j) * 32 + uu) * 4 + kk];
        }
        __syncthreads();
        for (int q = 0; q < 64; ++q) {
            float pv[4], cv[4];
#pragma unroll
            for (int mm = 0; mm < 4; ++mm) pv[mm] = Pt[(tm * 4 + mm) * 65 + q];
#pragma unroll
            for (int jj = 0; jj < 4; ++jj) cv[jj] = Ct[(tj * 4 + jj) * 65 + q];
#pragma unroll
            for (int mm = 0; mm < 4; ++mm)
#pragma unroll
                for (int jj = 0; jj < 4; ++jj)
                    acc[mm][jj] = fmaf(pv[mm], cv[jj], acc[mm][jj]);
        }
        __syncthreads();
    }
#pragma unroll
    for (int mm = 0; mm < 4; ++mm) {
        float4 w = make_float4(acc[mm][0], acc[mm][1], acc[mm][2], acc[mm][3]);
        *(float4*)(S + (size_t)b * 524288 + (size_t)(mt * 64 + tm * 4 + mm) * 512
                     + jt * 64 + tj * 4) = w;
    }
}

// ---------------------------------------------------------------------------
// K4: b-update with in-block squash recompute (no MS tensor, no mag kernel).
// grid (8 jt, 16 mc, 4 b) = 512 blocks.
__global__ void k_tbu(const float* __restrict__ Wg, float* __restrict__ ws)
{
    __shared__ float Ps[64 * 132];   // 8448
    __shared__ float Vs[64 * 68];    // 4352
    __shared__ float msS[64 * 32];   // 2048
    __shared__ float bup[64];
    const float* U  = ws + OFF_U;
    const float* SS = ws + OFF_SS;
    const float* S  = ws + OFF_S;
    float* Bg = ws + OFF_BG;
    const int jt = blockIdx.x, mc = blockIdx.y, b = blockIdx.z;
    const int t = threadIdx.x;
    const int tq = t & 31, tjv = t >> 5;
    const int m0 = mc * 64;
    if (t < 64) bup[t] = 0.f;
    // squash-scale slice for this 64-m chunk
    {
        const int uu = t & 31, rg = t >> 5;
#pragma unroll
        for (int mi = 0; mi < 8; ++mi) {
            const int r = rg * 8 + mi;
            const float* row = S + (size_t)b * 524288 + (size_t)(m0 + r) * 512;
            float mag = 0.f;
#pragma unroll
            for (int j = 0; j < 16; ++j) { const float v = row[j * 32 + uu]; mag = fmaf(v, v, mag); }
            msS[r * 32 + uu] = sqrtf(mag) / (1.f + mag);
        }
    }
    const float ssv = SS[b * 4 + (mc >> 2)];
    const float sc = sqrtf(ssv) / (1.f + ssv);
    __syncthreads();   // msS ready
#pragma unroll
    for (int i = 0; i < 8; ++i) {
        const int f4 = t + i * 256;
        const int r = f4 >> 5, q4 = f4 & 31;
        float4 v = *(const float4*)&U[(size_t)b * 131072 + (size_t)(m0 + r) * 128 + q4 * 4];
        v.x *= sc; v.y *= sc; v.z *= sc; v.w *= sc;
        *(float4*)&Ps[r * 132 + q4 * 4] = v;
    }
#pragma unroll
    for (int i = 0; i < 4; ++i) {
        const int f4 = t + i * 256;
        const int r = f4 >> 4, c4 = f4 & 15;
        const int m = m0 + r;
        float4 v = *(const float4*)&S[(size_t)b * 524288 + (size_t)m * 512 + jt * 64 + c4 * 4];
        const int ub = (c4 * 4) & 31;
        v.x *= msS[r * 32 + ub + 0]; v.y *= msS[r * 32 + ub + 1];
        v.z *= msS[r * 32 + ub + 2]; v.w *= msS[r * 32 + ub + 3];
        *(float4*)&Vs[r * 68 + c4 * 4] = v;
    }
    __syncthreads();
    float acc[4][8] = {};
#pragma unroll 2
    for (int m = 0; m < 64; ++m) {
        const float4 p4 = *(const float4*)&Ps[m * 132 + tq * 4];
        const float4 va = *(const float4*)&Vs[m * 68 + tjv * 8];
        const float4 vb = *(const float4*)&Vs[m * 68 + tjv * 8 + 4];
        const float pv[4] = {p4.x, p4.y, p4.z, p4.w};
        const float vv[8] = {va.x, va.y, va.z, va.w, vb.x, vb.y, vb.z, vb.w};
#pragma unroll
        for (int qi = 0; qi < 4; ++qi)
#pragma unroll
            for (int ji = 0; ji < 8; ++ji)
                acc[qi][ji] = fmaf(pv[qi], vv[ji], acc[qi][ji]);
    }
    const int k = tq >> 3;
    const int j_loc = tjv >> 2;
    const int j = jt * 2 + j_loc;
    const int u0 = (tjv & 3) * 8;
#pragma unroll
    for (int qi = 0; qi < 4; ++qi) {
        const int i = (tq & 7) * 4 + qi;
        const float* wp = Wg + ((i * 16 + j) * 32) * 4 + k;
        float s = 0.f;
#pragma unroll
        for (int ji = 0; ji < 8; ++ji)
            s = fmaf(wp[(u0 + ji) * 4], acc[qi][ji], s);
        s += __shfl_xor(s, 8);
        s += __shfl_xor(s, 16);
        s += __shfl_xor(s, 32);
        if ((t & 56) == 0) atomicAdd(&bup[i * 2 + j_loc], s);
    }
    __syncthreads();
    if (t < 64) {
        const int ii = t >> 1, jl = t & 1;
        atomicAdd(&Bg[b * 512 + ii * 16 + jt * 2 + jl], bup[t] * (1.f / 1024.f));
    }
}

// ---------------------------------------------------------------------------
// K5 (last iter): mag + mean fused -> G. grid (32 mt, 4 b).
__global__ void k_maggmean(float* __restrict__ ws)
{
    __shared__ float gacc[512];
    const float* S = ws + OFF_S;
    float* G = ws + OFF_G;
    const int t = threadIdx.x;
    gacc[t] = 0.f; gacc[t + 256] = 0.f;
    const int uu = t & 31, mlg = t >> 5;
    const int b = blockIdx.y;
    const int m0 = blockIdx.x * 32 + mlg * 4;
    float preg[16];
#pragma unroll
    for (int j = 0; j < 16; ++j) preg[j] = 0.f;
    __syncthreads();
#pragma unroll
    for (int mi = 0; mi < 4; ++mi) {
        const float* row = S + (size_t)b * 524288 + (size_t)(m0 + mi) * 512;
        float sv[16];
        float mag = 0.f;
#pragma unroll
        for (int j = 0; j < 16; ++j) { sv[j] = row[j * 32 + uu]; mag = fmaf(sv[j], sv[j], mag); }
        const float msc = sqrtf(mag) / (1.f + mag);
#pragma unroll
        for (int j = 0; j < 16; ++j) preg[j] = fmaf(sv[j], msc, preg[j]);
    }
#pragma unroll
    for (int j = 0; j < 16; ++j) atomicAdd(&gacc[j * 32 + uu], preg[j]);
    __syncthreads();
    atomicAdd(&G[b * 512 + t], gacc[t] * (1.f / 1024.f));
    atomicAdd(&G[b * 512 + 256 + t], gacc[t + 256] * (1.f / 1024.f));
}

// ---------------------------------------------------------------------------
// K6: UH[b][e] = sum_k Ws[e][k] * cond[b][i*32+k]. grid (8 slices, 4 b).
__global__ void k_uhat(const float* __restrict__ Wa, const float* __restrict__ Wsp,
                       float* __restrict__ ws)
{
    const float* G = ws + OFF_G;
    float* UH = ws + OFF_UH;
    const int b = blockIdx.y;
    const int t = threadIdx.x;
    __shared__ float g[512], cond[512], score[16], red[16];
    g[t] = G[b * 512 + t];
    g[t + 256] = G[b * 512 + 256 + t];
    __syncthreads();
    if (t < 16) {
        float s = 0.f;
        for (int uu = 0; uu < 32; ++uu) s = fmaf(g[t * 32 + uu], Wa[uu], s);
        red[t] = s;
    }
    __syncthreads();
    if (t == 0) {
        float mx = -1e30f;
        for (int j = 0; j < 16; ++j) mx = fmaxf(mx, red[j]);
        float sum = 0.f;
        for (int j = 0; j < 16; ++j) { score[j] = expf(red[j] - mx); sum += score[j]; }
        const float inv = 1.f / sum;
        for (int j = 0; j < 16; ++j) score[j] *= inv;
    }
    __syncthreads();
    cond[t] = g[t] * score[t >> 5];
    cond[t + 256] = g[t + 256] * score[(t + 256) >> 5];
    __syncthreads();
    const int e0 = blockIdx.x * 1024 + t * 4;
    const int i = e0 >> 9;
    const float* cp = cond + i * 32;
    const float* wp = Wsp + (size_t)e0 * 32;
    float res[4];
#pragma unroll
    for (int jj = 0; jj < 4; ++jj) {
        float s = 0.f;
#pragma unroll
        for (int k8 = 0; k8 < 8; ++k8) {
            const float4 w = *(const float4*)(wp + jj * 32 + k8 * 4);
            s = fmaf(w.x, cp[k8 * 4 + 0], s);
            s = fmaf(w.y, cp[k8 * 4 + 1], s);
            s = fmaf(w.z, cp[k8 * 4 + 2], s);
            s = fmaf(w.w, cp[k8 * 4 + 3], s);
        }
        res[jj] = s;
    }
    ((float4*)UH)[(b * 8192 + e0) >> 2] = make_float4(res[0], res[1], res[2], res[3]);
}

// ---------------------------------------------------------------------------
// K7: aspect routing (redundant per 64-block group) + direct out write.
// grid 256: b = bid>>6; each block writes 1024 float4 of out.
__global__ void k_route_out(float* __restrict__ ws, float* __restrict__ out)
{
    const float* UH = ws + OFF_UH;
    const int bid = blockIdx.x;
    const int t = threadIdx.x;
    __shared__ float uh[8192], ba[256], cc[256], sbuf[512], msc[32];
    const int b = bid >> 6;
#pragma unroll
    for (int i = 0; i < 8; ++i)
        ((float4*)uh)[i * 256 + t] = ((const float4*)UH)[b * 2048 + i * 256 + t];
    ba[t] = 0.f;
    __syncthreads();
    for (int it = 0; it < 3; ++it) {
        if (t < 16) {
            float mx = -1e30f;
            for (int j = 0; j < 16; ++j) mx = fmaxf(mx, ba[t * 16 + j]);
            float sum = 0.f;
            for (int j = 0; j < 16; ++j) { cc[t * 16 + j] = expf(ba[t * 16 + j] - mx); sum += cc[t * 16 + j]; }
            const float inv = 1.f / sum;
            for (int j = 0; j < 16; ++j) cc[t * 16 + j] *= inv;
        }
        __syncthreads();
        for (int h = 0; h < 2; ++h) {
            const int e = h * 256 + t;
            const int j = e >> 5;
            float s = 0.f;
            for (int i = 0; i < 16; ++i) s = fmaf(cc[i * 16 + j], uh[i * 512 + e], s);
            sbuf[e] = s;
        }
        __syncthreads();
        if (t < 32) {
            float mg = 0.f;
            for (int j = 0; j < 16; ++j) { const float x = sbuf[j * 32 + t]; mg = fmaf(x, x, mg); }
            msc[t] = sqrtf(mg) / (1.f + mg);
        }
        __syncthreads();
        for (int h = 0; h < 2; ++h) {
            const int e = h * 256 + t;
            sbuf[e] *= msc[e & 31];
        }
        __syncthreads();
        if (it < 2) {
            const int i = t >> 4, j = t & 15;
            float s = 0.f;
            for (int uu = 0; uu < 32; ++uu) s = fmaf(uh[i * 512 + j * 32 + uu], sbuf[j * 32 + uu], s);
            ba[t] += s;
            __syncthreads();
        }
    }
#pragma unroll
    for (int i = 0; i < 4; ++i) {
        const int idx = bid * 1024 + i * 256 + t;   // float4 index, 262144 total
        const int jv4 = idx & 127;                  // idx>>16 == bid>>6 == b
        ((float4*)out)[idx] = *(const float4*)&sbuf[jv4 * 4];
    }
}

// ---------------------------------------------------------------------------
extern "C" void kernel_launch(void* const* d_in, const int* in_sizes, int n_in,
                              void* d_out, int out_size, void* d_ws, size_t ws_size,
                              hipStream_t stream)
{
    const float* X   = (const float*)d_in[0];
    // d_in[1] = hidden — provably unused (softmax shift-invariance kills it)
    const float* Wp  = (const float*)d_in[2];
    const float* bp  = (const float*)d_in[3];
    const float* Wg  = (const float*)d_in[4];
    const float* Wa  = (const float*)d_in[5];
    const float* Wsp = (const float*)d_in[6];
    float* out = (float*)d_out;
    float* ws  = (float*)d_ws;

    k_primary_part<<<dim3(2, 16, 16), 256, 0, stream>>>(X, Wp, ws);
    k_reduceU<<<128, 256, 0, stream>>>(bp, ws);

    for (int it = 0; it < 3; ++it) {
        k_smatmul<<<dim3(16, 8, 4), 256, 0, stream>>>(Wg, ws);
        if (it < 2) k_tbu<<<dim3(8, 16, 4), 256, 0, stream>>>(Wg, ws);
        else        k_maggmean<<<dim3(32, 4), 256, 0, stream>>>(ws);
    }

    k_uhat<<<dim3(8, 4), 256, 0, stream>>>(Wa, Wsp, ws);
    k_route_out<<<256, 256, 0, stream>>>(ws, out);
}